// Round 1
// 178.331 us; speedup vs baseline: 1.0001x; 1.0001x over previous
//
#include <hip/hip_runtime.h>

#define NH    8
#define DH    64
#define DIMD  512
#define NCTX  2048
#define NB    4
#define NROWS (NB * NCTX)   // 8192
#define QKVN  (3 * DIMD)    // 1536

typedef __attribute__((ext_vector_type(8))) short bf16x8;
typedef __attribute__((ext_vector_type(4))) float f32x4;

#define INV_LN2 1.44269504f
#define SCLOG   (0.125f * INV_LN2)   // folded into Q at mgemm1 epilogue

__device__ __forceinline__ unsigned short f2bits(float f) {
  unsigned u = __float_as_uint(f);
  u += 0x7fffu + ((u >> 16) & 1u);      // round-to-nearest-even
  return (unsigned short)(u >> 16);
}
__device__ __forceinline__ float bits2f(unsigned short u) {
  return __uint_as_float(((unsigned)u) << 16);
}

// ---------------- LayerNorm -> bf16: one wave per row of 512 ----------------
__global__ __launch_bounds__(256) void ln_kernel(
    const float* __restrict__ x,
    const float* __restrict__ gamma,
    const float* __restrict__ beta,
    unsigned short* __restrict__ xn) {
  const int wid  = threadIdx.x >> 6;
  const int lane = threadIdx.x & 63;
  const int row  = blockIdx.x * 4 + wid;
  const float* xr = x + (size_t)row * DIMD + lane * 8;
  float v[8];
  const float4 a = *reinterpret_cast<const float4*>(xr);
  const float4 b = *reinterpret_cast<const float4*>(xr + 4);
  v[0] = a.x; v[1] = a.y; v[2] = a.z; v[3] = a.w;
  v[4] = b.x; v[5] = b.y; v[6] = b.z; v[7] = b.w;
  float s = 0.f;
#pragma unroll
  for (int i = 0; i < 8; ++i) s += v[i];
#pragma unroll
  for (int off = 32; off; off >>= 1) s += __shfl_down(s, off);
  s = __shfl(s, 0);
  const float mu = s * (1.f / DIMD);
  float ss = 0.f;
#pragma unroll
  for (int i = 0; i < 8; ++i) { float d = v[i] - mu; ss += d * d; }
#pragma unroll
  for (int off = 32; off; off >>= 1) ss += __shfl_down(ss, off);
  ss = __shfl(ss, 0);
  const float inv = rsqrtf(ss * (1.f / DIMD) + 1e-5f);
  const float4 g0 = *reinterpret_cast<const float4*>(gamma + lane * 8);
  const float4 g1 = *reinterpret_cast<const float4*>(gamma + lane * 8 + 4);
  const float4 b0 = *reinterpret_cast<const float4*>(beta + lane * 8);
  const float4 b1 = *reinterpret_cast<const float4*>(beta + lane * 8 + 4);
  float g[8] = {g0.x, g0.y, g0.z, g0.w, g1.x, g1.y, g1.z, g1.w};
  float be[8] = {b0.x, b0.y, b0.z, b0.w, b1.x, b1.y, b1.z, b1.w};
  bf16x8 o;
#pragma unroll
  for (int i = 0; i < 8; ++i)
    o[i] = (short)f2bits((v[i] - mu) * inv * g[i] + be[i]);
  *reinterpret_cast<bf16x8*>(xn + (size_t)row * DIMD + lane * 8) = o;
}

// ---------------- Fused transpose+cvt for BOTH weights (z picks matrix) ----------------
// in [R][C] fp32 -> out [C][R] bf16.  z=0: wqkv (C=1536), z=1: wout (C=512).
__global__ __launch_bounds__(256) void tconv_kernel(
    const float* __restrict__ in0, unsigned short* __restrict__ out0,
    const float* __restrict__ in1, unsigned short* __restrict__ out1) {
  const int z = blockIdx.z;
  const int C = z ? DIMD : QKVN;
  if (z && blockIdx.x >= DIMD / 64) return;
  const float* in = z ? in1 : in0;
  unsigned short* out = z ? out1 : out0;
  __shared__ float T[64][65];
  const int r0 = blockIdx.y * 64, c0 = blockIdx.x * 64;
  const int ty = threadIdx.x >> 4, tx = threadIdx.x & 15;
#pragma unroll
  for (int i = 0; i < 4; ++i) {
    const int r = ty + i * 16;
    const float4 v = *reinterpret_cast<const float4*>(
        in + (size_t)(r0 + r) * C + c0 + tx * 4);
    T[r][tx * 4 + 0] = v.x; T[r][tx * 4 + 1] = v.y;
    T[r][tx * 4 + 2] = v.z; T[r][tx * 4 + 3] = v.w;
  }
  __syncthreads();
#pragma unroll
  for (int i = 0; i < 4; ++i) {
    const int c = ty + i * 16;
    ushort4 o;
    o.x = f2bits(T[tx * 4 + 0][c]); o.y = f2bits(T[tx * 4 + 1][c]);
    o.z = f2bits(T[tx * 4 + 2][c]); o.w = f2bits(T[tx * 4 + 3][c]);
    *reinterpret_cast<ushort4*>(out + (size_t)(c0 + c) * DIMD + r0 + tx * 4) = o;
  }
}

// ---------------- V transpose + c-scale (pbprep folded in) ----------------
// c_j = bf16(exp2(beta*pb_j/ln2)); V'[d][j] = c_j * V[j][d]; hi==0 blocks emit cexp.
__global__ __launch_bounds__(256) void vtrans_kernel(
    const unsigned short* __restrict__ qkv,   // [NROWS, 1536] bf16
    const float* __restrict__ pb,             // [NB*NCTX] fp32
    const float* __restrict__ betap,
    unsigned short* __restrict__ cexp,        // [NB*NCTX] bf16 (out)
    unsigned short* __restrict__ vt) {        // [NB*NH*64][2048] bf16
  __shared__ unsigned short T[64][68];
  const int jt = blockIdx.x, hi = blockIdx.y, bi = blockIdx.z;
  const int ty = threadIdx.x >> 4, tx = threadIdx.x & 15;
  const int j0 = jt * 64;
#pragma unroll
  for (int i = 0; i < 4; ++i) {
    const int j = ty + i * 16;
    const ushort4 v = *reinterpret_cast<const ushort4*>(
        qkv + (size_t)(bi * NCTX + j0 + j) * QKVN + 2 * DIMD + hi * DH + tx * 4);
    T[j][tx * 4 + 0] = v.x; T[j][tx * 4 + 1] = v.y;
    T[j][tx * 4 + 2] = v.z; T[j][tx * 4 + 3] = v.w;
  }
  const float bl2 = betap[0] * INV_LN2;
  const float4 pv = *reinterpret_cast<const float4*>(pb + bi * NCTX + j0 + tx * 4);
  ushort4 cb;   // bf16-rounded c (matches round-11 numerics exactly)
  cb.x = f2bits(exp2f(bl2 * pv.x)); cb.y = f2bits(exp2f(bl2 * pv.y));
  cb.z = f2bits(exp2f(bl2 * pv.z)); cb.w = f2bits(exp2f(bl2 * pv.w));
  if (hi == 0 && ty == 0)
    *reinterpret_cast<ushort4*>(cexp + bi * NCTX + j0 + tx * 4) = cb;
  const float c0 = bits2f(cb.x), c1 = bits2f(cb.y), c2 = bits2f(cb.z), c3 = bits2f(cb.w);
  __syncthreads();
#pragma unroll
  for (int i = 0; i < 4; ++i) {
    const int d = ty + i * 16;
    ushort4 o;
    o.x = f2bits(bits2f(T[tx * 4 + 0][d]) * c0);
    o.y = f2bits(bits2f(T[tx * 4 + 1][d]) * c1);
    o.z = f2bits(bits2f(T[tx * 4 + 2][d]) * c2);
    o.w = f2bits(bits2f(T[tx * 4 + 3][d]) * c3);
    *reinterpret_cast<ushort4*>(
        vt + ((size_t)(bi * NH + hi) * DH + d) * NCTX + j0 + tx * 4) = o;
  }
}

// ---------------- MFMA GEMM, register-prefetch pipelined ----------------
__device__ __forceinline__ void storeC(float* C, size_t idx, float v) { C[idx] = v; }
__device__ __forceinline__ void storeC(unsigned short* C, size_t idx, float v) { C[idx] = f2bits(v); }

template <typename CT, bool QS>
__global__ __launch_bounds__(256) void mgemm_kernel(
    const unsigned short* __restrict__ A, const unsigned short* __restrict__ Bt,
    CT* __restrict__ C, int M, int N, int K) {
  __shared__ __align__(16) unsigned short As[128][72];
  __shared__ __align__(16) unsigned short Bs[128][72];
  const int tid  = threadIdx.x;
  const int wave = tid >> 6, lane = tid & 63;
  const int quad = lane >> 4, l16 = lane & 15;
  const int wr = wave >> 1, wc = wave & 1;
  const int tm0 = blockIdx.y * 128, tn0 = blockIdx.x * 128;
  const int srow = tid >> 3;
  const int schunk = (tid & 7) * 8;
  f32x4 acc[4][4];
#pragma unroll
  for (int i = 0; i < 4; ++i)
#pragma unroll
    for (int j = 0; j < 4; ++j) acc[i][j] = (f32x4){0.f, 0.f, 0.f, 0.f};

  bf16x8 ra[4], rb[4];
#pragma unroll
  for (int p = 0; p < 4; ++p) {
    const int r = srow + p * 32;
    ra[p] = *reinterpret_cast<const bf16x8*>(A + (size_t)(tm0 + r) * K + schunk);
    rb[p] = *reinterpret_cast<const bf16x8*>(Bt + (size_t)(tn0 + r) * K + schunk);
  }
  for (int k0 = 0; k0 < K; k0 += 64) {
#pragma unroll
    for (int p = 0; p < 4; ++p) {
      const int r = srow + p * 32;
      *reinterpret_cast<bf16x8*>(&As[r][schunk]) = ra[p];
      *reinterpret_cast<bf16x8*>(&Bs[r][schunk]) = rb[p];
    }
    __syncthreads();
    if (k0 + 64 < K) {      // prefetch next K-slab; latency hidden behind MFMAs
#pragma unroll
      for (int p = 0; p < 4; ++p) {
        const int r = srow + p * 32;
        ra[p] = *reinterpret_cast<const bf16x8*>(A + (size_t)(tm0 + r) * K + k0 + 64 + schunk);
        rb[p] = *reinterpret_cast<const bf16x8*>(Bt + (size_t)(tn0 + r) * K + k0 + 64 + schunk);
      }
    }
#pragma unroll
    for (int kc = 0; kc < 2; ++kc) {
      const int kk = kc * 32 + quad * 8;
      bf16x8 af[4], bfr[4];
#pragma unroll
      for (int i = 0; i < 4; ++i)
        af[i] = *reinterpret_cast<const bf16x8*>(&As[wr * 64 + i * 16 + l16][kk]);
#pragma unroll
      for (int j = 0; j < 4; ++j)
        bfr[j] = *reinterpret_cast<const bf16x8*>(&Bs[wc * 64 + j * 16 + l16][kk]);
#pragma unroll
      for (int i = 0; i < 4; ++i)
#pragma unroll
        for (int j = 0; j < 4; ++j)
          acc[i][j] = __builtin_amdgcn_mfma_f32_16x16x32_bf16(af[i], bfr[j], acc[i][j], 0, 0, 0);
    }
    __syncthreads();
  }
#pragma unroll
  for (int j = 0; j < 4; ++j) {
    const int col = tn0 + wc * 64 + j * 16 + l16;
    const float scl = (QS && col < DIMD) ? SCLOG : 1.0f;
#pragma unroll
    for (int i = 0; i < 4; ++i)
#pragma unroll
      for (int r = 0; r < 4; ++r)
        storeC(C, (size_t)(tm0 + wr * 64 + i * 16 + quad * 4 + r) * N + col,
               acc[i][j][r] * scl);
  }
}

// ---------------- MFMA flash attention: 2x2 wave split ----------------
// 64-query block; wave = (query-half: 32q, key-half: 32k).
// Round 13: LDS-traffic diet. (1) bv hoisted across u (V-half read once);
// (2) P redistribution fully in-register via cvt_pk_bf16 + permlane16/32_swap
//     (kills the Pw round-trip: 4 b64 W + 2 b128 R per wave per kt);
// (3) c-row read at l16-uniform address from 64-short crow (broadcast; D cols
//     1..15 carry duplicate sums, unused -> 15 zero rows + init deleted);
// (4) Ob stride 68 de-aliases the 128B-stride epilogue quad conflict.
// LDS: 39936 -> 18560 B/block.
__global__ __launch_bounds__(256, 4) void fattn_kernel(
    const unsigned short* __restrict__ qkv,   // [NROWS, 1536] bf16 (Q pre-scaled by SCLOG)
    const unsigned short* __restrict__ vtg,   // [NB*NH*64][2048] bf16 (c-scaled V^T)
    const unsigned short* __restrict__ cexp,  // [NB*NCTX] bf16
    unsigned short* __restrict__ out) {       // [NROWS, 512] bf16
  // LDS layout (shorts): [0,4608)    Kl[64][72]
  //                      [4608,9216) Vt[64][72]
  //                      [9216,9280) crow[64]
  // epilogue alias:      Ob bf16 [64][68] = [0,4352); lb fp32[128] = [4352,4608)
  __shared__ __align__(16) unsigned short lds[9280];
  unsigned short (*Kl)[72] = (unsigned short (*)[72])(lds);
  unsigned short (*Vt)[72] = (unsigned short (*)[72])(lds + 4608);
  unsigned short* crow = lds + 9216;
  unsigned short* Ob = lds;               // alias over Kl (dead after loop)
  float* lb = (float*)(lds + 4352);

  const int qt = blockIdx.x, hi = blockIdx.y, bi = blockIdx.z;
  const int tid  = threadIdx.x;
  const int wave = tid >> 6, lane = tid & 63;
  const int quad = lane >> 4, l16 = lane & 15;
  const int wq = wave & 1, wk = wave >> 1;
  const int qrow0 = qt * 64;
  const unsigned short* base  = qkv + (size_t)bi * NCTX * QKVN + hi * DH;
  const unsigned short* vbase = vtg + (size_t)(bi * NH + hi) * DH * NCTX;
  const unsigned short* cbase = cexp + (size_t)bi * NCTX;
  const int sr = tid >> 2;            // staging row 0..63
  const int sc4 = (tid & 3) * 16;     // staging col base (shorts)

  // ---- Q B-frags straight from global (one-time, 64B-line aligned rows) ----
  bf16x8 qf[2][2];
#pragma unroll
  for (int u = 0; u < 2; ++u)
#pragma unroll
    for (int h = 0; h < 2; ++h)
      qf[u][h] = *reinterpret_cast<const bf16x8*>(
          base + (size_t)(qrow0 + wq * 32 + u * 16 + l16) * QKVN + h * 32 + quad * 8);
  // ---- prefetch + publish tile 0 ----
  bf16x8 pk0, pk1, pv0, pv1; ushort4 pc;
  {
    const unsigned short* kr = base + (size_t)sr * QKVN + DIMD + sc4;
    pk0 = *reinterpret_cast<const bf16x8*>(kr);
    pk1 = *reinterpret_cast<const bf16x8*>(kr + 8);
    const unsigned short* vr = vbase + (size_t)sr * NCTX + sc4;
    pv0 = *reinterpret_cast<const bf16x8*>(vr);
    pv1 = *reinterpret_cast<const bf16x8*>(vr + 8);
    if (tid < 16) pc = *reinterpret_cast<const ushort4*>(cbase + tid * 4);
    *reinterpret_cast<bf16x8*>(&Kl[sr][sc4])     = pk0;
    *reinterpret_cast<bf16x8*>(&Kl[sr][sc4 + 8]) = pk1;
    *reinterpret_cast<bf16x8*>(&Vt[sr][sc4])     = pv0;
    *reinterpret_cast<bf16x8*>(&Vt[sr][sc4 + 8]) = pv1;
    if (tid < 16) *reinterpret_cast<ushort4*>(&crow[tid * 4]) = pc;
  }
  __syncthreads();

  f32x4 O[2][4], accl[2];
#pragma unroll
  for (int u = 0; u < 2; ++u) {
    accl[u] = (f32x4){0.f, 0.f, 0.f, 0.f};
#pragma unroll
    for (int s = 0; s < 4; ++s) O[u][s] = (f32x4){0.f, 0.f, 0.f, 0.f};
  }

  for (int kt = 0; kt < 32; ++kt) {
    // ---- prefetch next tile ----
    if (kt < 31) {
      const int krow1 = (kt + 1) * 64;
      const unsigned short* kr = base + (size_t)(krow1 + sr) * QKVN + DIMD + sc4;
      pk0 = *reinterpret_cast<const bf16x8*>(kr);
      pk1 = *reinterpret_cast<const bf16x8*>(kr + 8);
      const unsigned short* vr = vbase + (size_t)sr * NCTX + krow1 + sc4;
      pv0 = *reinterpret_cast<const bf16x8*>(vr);
      pv1 = *reinterpret_cast<const bf16x8*>(vr + 8);
      if (tid < 16) pc = *reinterpret_cast<const ushort4*>(cbase + krow1 + tid * 4);
    }
    // ---- S^T = K Q^T on wave's 32 keys x 32 queries ----
    f32x4 sfr[2][2];   // [t key-sub][u query-sub]
#pragma unroll
    for (int t = 0; t < 2; ++t) {
      const bf16x8 kf0 = *reinterpret_cast<const bf16x8*>(
          &Kl[wk * 32 + t * 16 + l16][quad * 8]);
      const bf16x8 kf1 = *reinterpret_cast<const bf16x8*>(
          &Kl[wk * 32 + t * 16 + l16][32 + quad * 8]);
#pragma unroll
      for (int u = 0; u < 2; ++u) {
        f32x4 acc = (f32x4){0.f, 0.f, 0.f, 0.f};
        acc = __builtin_amdgcn_mfma_f32_16x16x32_bf16(kf0, qf[u][0], acc, 0, 0, 0);
        acc = __builtin_amdgcn_mfma_f32_16x16x32_bf16(kf1, qf[u][1], acc, 0, 0, 0);
        sfr[t][u] = acc;
      }
    }
    // ---- P = exp2(S), redistributed fully in-register ----
    // Source: lane(quad,l16) holds P^T[key-local = t*16+4*quad+r][query l16].
    // cvt_pk packs key pairs; permlane32_swap then permlane16_swap route key
    // groups so lane(quad,l16) ends with A-frag P[query=l16][key=8*quad+e].
    bf16x8 pf[2];
#pragma unroll
    for (int u = 0; u < 2; ++u) {
      unsigned x0, x1, y0, y1;
      {
        const float e0 = exp2f(sfr[0][u][0]), e1 = exp2f(sfr[0][u][1]);
        const float e2 = exp2f(sfr[0][u][2]), e3 = exp2f(sfr[0][u][3]);
        const float f0 = exp2f(sfr[1][u][0]), f1 = exp2f(sfr[1][u][1]);
        const float f2 = exp2f(sfr[1][u][2]), f3 = exp2f(sfr[1][u][3]);
        asm("v_cvt_pk_bf16_f32 %0, %1, %2" : "=v"(x0) : "v"(e0), "v"(e1));
        asm("v_cvt_pk_bf16_f32 %0, %1, %2" : "=v"(x1) : "v"(e2), "v"(e3));
        asm("v_cvt_pk_bf16_f32 %0, %1, %2" : "=v"(y0) : "v"(f0), "v"(f1));
        asm("v_cvt_pk_bf16_f32 %0, %1, %2" : "=v"(y1) : "v"(f2), "v"(f3));
      }
      // groups by quad before: x_j=[g0,g1,g4,g5]? no: a0j=[g0,g1,g2,g3], a1j=[g4,g5,g6,g7]
      asm("v_permlane32_swap_b32 %0, %1" : "+v"(x0), "+v"(y0));  // x0=[g0,g1,g4,g5] y0=[g2,g3,g6,g7]
      asm("v_permlane32_swap_b32 %0, %1" : "+v"(x1), "+v"(y1));
      asm("v_permlane16_swap_b32 %0, %1" : "+v"(x0), "+v"(y0));  // x0=[g0,g2,g4,g6] y0=[g1,g3,g5,g7]
      asm("v_permlane16_swap_b32 %0, %1" : "+v"(x1), "+v"(y1));
      union { unsigned q[4]; bf16x8 v; } pu;
      pu.q[0] = x0; pu.q[1] = x1; pu.q[2] = y0; pu.q[3] = y1;
      pf[u] = pu.v;
    }
    // ---- O += P V' over wave's keys; denominator via uniform-address c-row ----
    {
      const bf16x8 cf = *reinterpret_cast<const bf16x8*>(&crow[wk * 32 + quad * 8]);
      accl[0] = __builtin_amdgcn_mfma_f32_16x16x32_bf16(pf[0], cf, accl[0], 0, 0, 0);
      accl[1] = __builtin_amdgcn_mfma_f32_16x16x32_bf16(pf[1], cf, accl[1], 0, 0, 0);
#pragma unroll
      for (int s = 0; s < 4; ++s) {
        const bf16x8 bv = *reinterpret_cast<const bf16x8*>(
            &Vt[s * 16 + l16][wk * 32 + quad * 8]);
        O[0][s] = __builtin_amdgcn_mfma_f32_16x16x32_bf16(pf[0], bv, O[0][s], 0, 0, 0);
        O[1][s] = __builtin_amdgcn_mfma_f32_16x16x32_bf16(pf[1], bv, O[1][s], 0, 0, 0);
      }
    }
    // ---- publish prefetched tile ----
    if (kt < 31) {
      __syncthreads();
      *reinterpret_cast<bf16x8*>(&Kl[sr][sc4])     = pk0;
      *reinterpret_cast<bf16x8*>(&Kl[sr][sc4 + 8]) = pk1;
      *reinterpret_cast<bf16x8*>(&Vt[sr][sc4])     = pv0;
      *reinterpret_cast<bf16x8*>(&Vt[sr][sc4 + 8]) = pv1;
      if (tid < 16) *reinterpret_cast<ushort4*>(&crow[tid * 4]) = pc;
      __syncthreads();
    }
  }
  // ---- combine key-halves via dedicated Ob (bf16, stride 68) + lb (fp32) ----
  __syncthreads();
  if (wk == 1) {
#pragma unroll
    for (int u = 0; u < 2; ++u) {
#pragma unroll
      for (int s = 0; s < 4; ++s)
#pragma unroll
        for (int r = 0; r < 4; ++r)
          Ob[(wq * 32 + u * 16 + quad * 4 + r) * 68 + s * 16 + l16] = f2bits(O[u][s][r]);
      if (l16 == 0)
#pragma unroll
        for (int r = 0; r < 4; ++r)
          lb[64 + wq * 32 + u * 16 + quad * 4 + r] = accl[u][r];
    }
  } else {
#pragma unroll
    for (int u = 0; u < 2; ++u)
      if (l16 == 0)
#pragma unroll
        for (int r = 0; r < 4; ++r)
          lb[wq * 32 + u * 16 + quad * 4 + r] = accl[u][r];
  }
  __syncthreads();
  if (wk == 0) {
#pragma unroll
    for (int u = 0; u < 2; ++u)
#pragma unroll
      for (int r = 0; r < 4; ++r) {
        const int ql = wq * 32 + u * 16 + quad * 4 + r;
        const float linv = 1.f / (lb[ql] + lb[64 + ql]);
        const size_t orow = ((size_t)bi * NCTX + qrow0 + ql) * DIMD + hi * DH;
#pragma unroll
        for (int s = 0; s < 4; ++s)
          out[orow + s * 16 + l16] =
              f2bits((O[u][s][r] + bits2f(Ob[ql * 68 + s * 16 + l16])) * linv);
      }
  }
}

extern "C" void kernel_launch(void* const* d_in, const int* in_sizes, int n_in,
                              void* d_out, int out_size, void* d_ws, size_t ws_size,
                              hipStream_t stream) {
  const float* x     = (const float*)d_in[0];
  const float* pose  = (const float*)d_in[1];
  const float* gam   = (const float*)d_in[2];
  const float* bet   = (const float*)d_in[3];
  const float* wqkv  = (const float*)d_in[4];
  const float* wout  = (const float*)d_in[5];
  const float* betap = (const float*)d_in[6];
  float* out = (float*)d_out;

  unsigned short* xn    = (unsigned short*)d_ws;             // 8 MB (reused as aout)
  unsigned short* qkvb  = xn + (size_t)NROWS * DIMD;         // 24 MB
  unsigned short* wqkvT = qkvb + (size_t)NROWS * QKVN;       // 1.5 MB
  unsigned short* woutT = wqkvT + (size_t)QKVN * DIMD;       // 0.5 MB
  unsigned short* vtg   = woutT + (size_t)DIMD * DIMD;       // 8 MB  c-scaled V^T
  unsigned short* cexp  = vtg + (size_t)NB * NH * DH * NCTX; // 16 KB
  unsigned short* aout  = xn;                                // alias: xn dead after GEMM1

  ln_kernel<<<NROWS / 4, 256, 0, stream>>>(x, gam, bet, xn);
  tconv_kernel<<<dim3(QKVN / 64, DIMD / 64, 2), 256, 0, stream>>>(
      wqkv, wqkvT, wout, woutT);
  mgemm_kernel<unsigned short, true><<<dim3(QKVN / 128, NROWS / 128), 256, 0, stream>>>(
      xn, wqkvT, qkvb, NROWS, QKVN, DIMD);
  vtrans_kernel<<<dim3(NCTX / 64, NH, NB), 256, 0, stream>>>(
      qkvb, pose, betap, cexp, vtg);
  fattn_kernel<<<dim3(NCTX / 64, NH, NB), 256, 0, stream>>>(qkvb, vtg, cexp, aout);
  mgemm_kernel<float, false><<<dim3(DIMD / 128, NROWS / 128), 256, 0, stream>>>(
      aout, woutT, out, NROWS, DIMD, DIMD);
}

// Round 2
// 177.909 us; speedup vs baseline: 1.0025x; 1.0024x over previous
//
#include <hip/hip_runtime.h>

#define NH    8
#define DH    64
#define DIMD  512
#define NCTX  2048
#define NB    4
#define NROWS (NB * NCTX)   // 8192
#define QKVN  (3 * DIMD)    // 1536

typedef __attribute__((ext_vector_type(8))) short bf16x8;
typedef __attribute__((ext_vector_type(4))) float f32x4;

#define INV_LN2 1.44269504f
#define SCLOG   (0.125f * INV_LN2)   // folded into Q at mgemm1 epilogue

__device__ __forceinline__ unsigned short f2bits(float f) {
  unsigned u = __float_as_uint(f);
  u += 0x7fffu + ((u >> 16) & 1u);      // round-to-nearest-even
  return (unsigned short)(u >> 16);
}
__device__ __forceinline__ float bits2f(unsigned short u) {
  return __uint_as_float(((unsigned)u) << 16);
}

// ---- global_load_lds wrappers (width 16 / 4). LDS base must be wave-uniform;
// ---- global src is per-lane (pre-swizzled source = swizzled LDS, rule #21).
__device__ __forceinline__ void gll16(const void* g, void* l) {
  __builtin_amdgcn_global_load_lds(
      (const __attribute__((address_space(1))) unsigned int*)g,
      (__attribute__((address_space(3))) unsigned int*)l, 16, 0, 0);
}
__device__ __forceinline__ void gll4(const void* g, void* l) {
  __builtin_amdgcn_global_load_lds(
      (const __attribute__((address_space(1))) unsigned int*)g,
      (__attribute__((address_space(3))) unsigned int*)l, 4, 0, 0);
}

// ---------------- LayerNorm -> bf16: one wave per row of 512 ----------------
__global__ __launch_bounds__(256) void ln_kernel(
    const float* __restrict__ x,
    const float* __restrict__ gamma,
    const float* __restrict__ beta,
    unsigned short* __restrict__ xn) {
  const int wid  = threadIdx.x >> 6;
  const int lane = threadIdx.x & 63;
  const int row  = blockIdx.x * 4 + wid;
  const float* xr = x + (size_t)row * DIMD + lane * 8;
  float v[8];
  const float4 a = *reinterpret_cast<const float4*>(xr);
  const float4 b = *reinterpret_cast<const float4*>(xr + 4);
  v[0] = a.x; v[1] = a.y; v[2] = a.z; v[3] = a.w;
  v[4] = b.x; v[5] = b.y; v[6] = b.z; v[7] = b.w;
  float s = 0.f;
#pragma unroll
  for (int i = 0; i < 8; ++i) s += v[i];
#pragma unroll
  for (int off = 32; off; off >>= 1) s += __shfl_down(s, off);
  s = __shfl(s, 0);
  const float mu = s * (1.f / DIMD);
  float ss = 0.f;
#pragma unroll
  for (int i = 0; i < 8; ++i) { float d = v[i] - mu; ss += d * d; }
#pragma unroll
  for (int off = 32; off; off >>= 1) ss += __shfl_down(ss, off);
  ss = __shfl(ss, 0);
  const float inv = rsqrtf(ss * (1.f / DIMD) + 1e-5f);
  const float4 g0 = *reinterpret_cast<const float4*>(gamma + lane * 8);
  const float4 g1 = *reinterpret_cast<const float4*>(gamma + lane * 8 + 4);
  const float4 b0 = *reinterpret_cast<const float4*>(beta + lane * 8);
  const float4 b1 = *reinterpret_cast<const float4*>(beta + lane * 8 + 4);
  float g[8] = {g0.x, g0.y, g0.z, g0.w, g1.x, g1.y, g1.z, g1.w};
  float be[8] = {b0.x, b0.y, b0.z, b0.w, b1.x, b1.y, b1.z, b1.w};
  bf16x8 o;
#pragma unroll
  for (int i = 0; i < 8; ++i)
    o[i] = (short)f2bits((v[i] - mu) * inv * g[i] + be[i]);
  *reinterpret_cast<bf16x8*>(xn + (size_t)row * DIMD + lane * 8) = o;
}

// ---------------- Fused transpose+cvt for BOTH weights (z picks matrix) ----------------
__global__ __launch_bounds__(256) void tconv_kernel(
    const float* __restrict__ in0, unsigned short* __restrict__ out0,
    const float* __restrict__ in1, unsigned short* __restrict__ out1) {
  const int z = blockIdx.z;
  const int C = z ? DIMD : QKVN;
  if (z && blockIdx.x >= DIMD / 64) return;
  const float* in = z ? in1 : in0;
  unsigned short* out = z ? out1 : out0;
  __shared__ float T[64][65];
  const int r0 = blockIdx.y * 64, c0 = blockIdx.x * 64;
  const int ty = threadIdx.x >> 4, tx = threadIdx.x & 15;
#pragma unroll
  for (int i = 0; i < 4; ++i) {
    const int r = ty + i * 16;
    const float4 v = *reinterpret_cast<const float4*>(
        in + (size_t)(r0 + r) * C + c0 + tx * 4);
    T[r][tx * 4 + 0] = v.x; T[r][tx * 4 + 1] = v.y;
    T[r][tx * 4 + 2] = v.z; T[r][tx * 4 + 3] = v.w;
  }
  __syncthreads();
#pragma unroll
  for (int i = 0; i < 4; ++i) {
    const int c = ty + i * 16;
    ushort4 o;
    o.x = f2bits(T[tx * 4 + 0][c]); o.y = f2bits(T[tx * 4 + 1][c]);
    o.z = f2bits(T[tx * 4 + 2][c]); o.w = f2bits(T[tx * 4 + 3][c]);
    *reinterpret_cast<ushort4*>(out + (size_t)(c0 + c) * DIMD + r0 + tx * 4) = o;
  }
}

// ---------------- V transpose + c-scale (pbprep folded in) ----------------
__global__ __launch_bounds__(256) void vtrans_kernel(
    const unsigned short* __restrict__ qkv,   // [NROWS, 1536] bf16
    const float* __restrict__ pb,             // [NB*NCTX] fp32
    const float* __restrict__ betap,
    unsigned short* __restrict__ cexp,        // [NB*NCTX] bf16 (out)
    unsigned short* __restrict__ vt) {        // [NB*NH*64][2048] bf16
  __shared__ unsigned short T[64][68];
  const int jt = blockIdx.x, hi = blockIdx.y, bi = blockIdx.z;
  const int ty = threadIdx.x >> 4, tx = threadIdx.x & 15;
  const int j0 = jt * 64;
#pragma unroll
  for (int i = 0; i < 4; ++i) {
    const int j = ty + i * 16;
    const ushort4 v = *reinterpret_cast<const ushort4*>(
        qkv + (size_t)(bi * NCTX + j0 + j) * QKVN + 2 * DIMD + hi * DH + tx * 4);
    T[j][tx * 4 + 0] = v.x; T[j][tx * 4 + 1] = v.y;
    T[j][tx * 4 + 2] = v.z; T[j][tx * 4 + 3] = v.w;
  }
  const float bl2 = betap[0] * INV_LN2;
  const float4 pv = *reinterpret_cast<const float4*>(pb + bi * NCTX + j0 + tx * 4);
  ushort4 cb;   // bf16-rounded c (matches round-11 numerics exactly)
  cb.x = f2bits(exp2f(bl2 * pv.x)); cb.y = f2bits(exp2f(bl2 * pv.y));
  cb.z = f2bits(exp2f(bl2 * pv.z)); cb.w = f2bits(exp2f(bl2 * pv.w));
  if (hi == 0 && ty == 0)
    *reinterpret_cast<ushort4*>(cexp + bi * NCTX + j0 + tx * 4) = cb;
  const float c0 = bits2f(cb.x), c1 = bits2f(cb.y), c2 = bits2f(cb.z), c3 = bits2f(cb.w);
  __syncthreads();
#pragma unroll
  for (int i = 0; i < 4; ++i) {
    const int d = ty + i * 16;
    ushort4 o;
    o.x = f2bits(bits2f(T[tx * 4 + 0][d]) * c0);
    o.y = f2bits(bits2f(T[tx * 4 + 1][d]) * c1);
    o.z = f2bits(bits2f(T[tx * 4 + 2][d]) * c2);
    o.w = f2bits(bits2f(T[tx * 4 + 3][d]) * c3);
    *reinterpret_cast<ushort4*>(
        vt + ((size_t)(bi * NH + hi) * DH + d) * NCTX + j0 + tx * 4) = o;
  }
}

// ---------------- MFMA GEMM, register-prefetch pipelined (kept for GEMM2:
// ---------------- grid 256 blocks = 1/CU, 2-phase gll stall would be exposed) ----
__device__ __forceinline__ void storeC(float* C, size_t idx, float v) { C[idx] = v; }
__device__ __forceinline__ void storeC(unsigned short* C, size_t idx, float v) { C[idx] = f2bits(v); }

template <typename CT, bool QS>
__global__ __launch_bounds__(256) void mgemm_kernel(
    const unsigned short* __restrict__ A, const unsigned short* __restrict__ Bt,
    CT* __restrict__ C, int M, int N, int K) {
  __shared__ __align__(16) unsigned short As[128][72];
  __shared__ __align__(16) unsigned short Bs[128][72];
  const int tid  = threadIdx.x;
  const int wave = tid >> 6, lane = tid & 63;
  const int quad = lane >> 4, l16 = lane & 15;
  const int wr = wave >> 1, wc = wave & 1;
  const int tm0 = blockIdx.y * 128, tn0 = blockIdx.x * 128;
  const int srow = tid >> 3;
  const int schunk = (tid & 7) * 8;
  f32x4 acc[4][4];
#pragma unroll
  for (int i = 0; i < 4; ++i)
#pragma unroll
    for (int j = 0; j < 4; ++j) acc[i][j] = (f32x4){0.f, 0.f, 0.f, 0.f};

  bf16x8 ra[4], rb[4];
#pragma unroll
  for (int p = 0; p < 4; ++p) {
    const int r = srow + p * 32;
    ra[p] = *reinterpret_cast<const bf16x8*>(A + (size_t)(tm0 + r) * K + schunk);
    rb[p] = *reinterpret_cast<const bf16x8*>(Bt + (size_t)(tn0 + r) * K + schunk);
  }
  for (int k0 = 0; k0 < K; k0 += 64) {
#pragma unroll
    for (int p = 0; p < 4; ++p) {
      const int r = srow + p * 32;
      *reinterpret_cast<bf16x8*>(&As[r][schunk]) = ra[p];
      *reinterpret_cast<bf16x8*>(&Bs[r][schunk]) = rb[p];
    }
    __syncthreads();
    if (k0 + 64 < K) {
#pragma unroll
      for (int p = 0; p < 4; ++p) {
        const int r = srow + p * 32;
        ra[p] = *reinterpret_cast<const bf16x8*>(A + (size_t)(tm0 + r) * K + k0 + 64 + schunk);
        rb[p] = *reinterpret_cast<const bf16x8*>(Bt + (size_t)(tn0 + r) * K + k0 + 64 + schunk);
      }
    }
#pragma unroll
    for (int kc = 0; kc < 2; ++kc) {
      const int kk = kc * 32 + quad * 8;
      bf16x8 af[4], bfr[4];
#pragma unroll
      for (int i = 0; i < 4; ++i)
        af[i] = *reinterpret_cast<const bf16x8*>(&As[wr * 64 + i * 16 + l16][kk]);
#pragma unroll
      for (int j = 0; j < 4; ++j)
        bfr[j] = *reinterpret_cast<const bf16x8*>(&Bs[wc * 64 + j * 16 + l16][kk]);
#pragma unroll
      for (int i = 0; i < 4; ++i)
#pragma unroll
        for (int j = 0; j < 4; ++j)
          acc[i][j] = __builtin_amdgcn_mfma_f32_16x16x32_bf16(af[i], bfr[j], acc[i][j], 0, 0, 0);
    }
    __syncthreads();
  }
#pragma unroll
  for (int j = 0; j < 4; ++j) {
    const int col = tn0 + wc * 64 + j * 16 + l16;
    const float scl = (QS && col < DIMD) ? SCLOG : 1.0f;
#pragma unroll
    for (int i = 0; i < 4; ++i)
#pragma unroll
      for (int r = 0; r < 4; ++r)
        storeC(C, (size_t)(tm0 + wr * 64 + i * 16 + quad * 4 + r) * N + col,
               acc[i][j][r] * scl);
  }
}

// ---------------- m97-structure gll GEMM for GEMM1 (768 blocks = 3/CU) ----------
// global_load_lds width-16, linear LDS [128][64], XOR-swizzled both sides.
template <typename CT, bool QS>
__global__ __launch_bounds__(256) void ggemm_kernel(
    const unsigned short* __restrict__ A, const unsigned short* __restrict__ Bt,
    CT* __restrict__ C, int M, int N, int K) {
  __shared__ __align__(16) unsigned short As[128 * 64];
  __shared__ __align__(16) unsigned short Bs[128 * 64];
  const int tid  = threadIdx.x;
  const int wave = tid >> 6, lane = tid & 63;
  const int quad = lane >> 4, l16 = lane & 15;
  const int wr = wave >> 1, wc = wave & 1;
  const int tm0 = blockIdx.y * 128, tn0 = blockIdx.x * 128;
  // staging: inst i covers LDS rows i*32 + wave*8 + (lane>>3); 16B chunk (lane&7)
  // source byte within 128B row pre-swizzled: cb ^ ((row&7)<<4), row&7 == lane>>3
  const int srow = wave * 8 + (lane >> 3);
  const int ssh  = (((lane & 7) * 16) ^ ((lane >> 3) << 4)) >> 1;  // shorts
  const unsigned short* ap = A + (size_t)(tm0 + srow) * K + ssh;
  const unsigned short* bp = Bt + (size_t)(tn0 + srow) * K + ssh;
  // read-side swizzle: row&7 == l16&7
  const int xs = (l16 & 7) << 3;
  f32x4 acc[4][4];
#pragma unroll
  for (int i = 0; i < 4; ++i)
#pragma unroll
    for (int j = 0; j < 4; ++j) acc[i][j] = (f32x4){0.f, 0.f, 0.f, 0.f};

  for (int k0 = 0; k0 < K; k0 += 64) {
#pragma unroll
    for (int i = 0; i < 4; ++i) {
      gll16(ap + (size_t)(i * 32) * K + k0, &As[i * 2048 + wave * 512]);
      gll16(bp + (size_t)(i * 32) * K + k0, &Bs[i * 2048 + wave * 512]);
    }
    __syncthreads();          // drains vmcnt -> slab valid
#pragma unroll
    for (int kc = 0; kc < 2; ++kc) {
      const int kk = ((kc * 32 + quad * 8) ^ xs);
      bf16x8 af[4], bfr[4];
#pragma unroll
      for (int i = 0; i < 4; ++i)
        af[i] = *reinterpret_cast<const bf16x8*>(&As[(wr * 64 + i * 16 + l16) * 64 + kk]);
#pragma unroll
      for (int j = 0; j < 4; ++j)
        bfr[j] = *reinterpret_cast<const bf16x8*>(&Bs[(wc * 64 + j * 16 + l16) * 64 + kk]);
#pragma unroll
      for (int i = 0; i < 4; ++i)
#pragma unroll
        for (int j = 0; j < 4; ++j)
          acc[i][j] = __builtin_amdgcn_mfma_f32_16x16x32_bf16(af[i], bfr[j], acc[i][j], 0, 0, 0);
    }
    __syncthreads();          // all reads done before next slab overwrites
  }
#pragma unroll
  for (int j = 0; j < 4; ++j) {
    const int col = tn0 + wc * 64 + j * 16 + l16;
    const float scl = (QS && col < DIMD) ? SCLOG : 1.0f;
#pragma unroll
    for (int i = 0; i < 4; ++i)
#pragma unroll
      for (int r = 0; r < 4; ++r)
        storeC(C, (size_t)(tm0 + wr * 64 + i * 16 + quad * 4 + r) * N + col,
               acc[i][j][r] * scl);
  }
}

// ---------------- MFMA flash attention: 2x2 wave split, gll double-buffer ------
// Round 14: global_load_lds staging (no VGPR round-trip, no ds_writes), double-
// buffered linear LDS, ONE __syncthreads per k-tile (its vmcnt(0)+lgkmcnt(0)
// drain IS the 2-phase wait). Linear 128B rows would 16-way conflict -> XOR
// swizzle byte^((row&7)<<4) applied on BOTH sides via pre-swizzled global src
// (rule #21). Values bit-identical to round 13.
__global__ __launch_bounds__(256, 4) void fattn_kernel(
    const unsigned short* __restrict__ qkv,   // [NROWS, 1536] bf16 (Q pre-scaled by SCLOG)
    const unsigned short* __restrict__ vtg,   // [NB*NH*64][2048] bf16 (c-scaled V^T)
    const unsigned short* __restrict__ cexp,  // [NB*NCTX] bf16
    unsigned short* __restrict__ out) {       // [NROWS, 512] bf16
  // per buffer (shorts): K [64][64] @0, V [64][64] @4096, c[64] @8192 (+pad)
  __shared__ __align__(16) unsigned short lds[2][8320];

  const int qt = blockIdx.x, hi = blockIdx.y, bi = blockIdx.z;
  const int tid  = threadIdx.x;
  const int wave = tid >> 6, lane = tid & 63;
  const int quad = lane >> 4, l16 = lane & 15;
  const int wq = wave & 1, wk = wave >> 1;
  const int qrow0 = qt * 64;
  const unsigned short* base  = qkv + (size_t)bi * NCTX * QKVN + hi * DH;
  const unsigned short* vbase = vtg + (size_t)(bi * NH + hi) * DH * NCTX;
  const unsigned short* cbase = cexp + (size_t)bi * NCTX;

  // ---- staging decomposition: per gll inst, wave covers 8 rows x 128B ----
  const int sr8 = lane >> 3;                                    // row&7
  const int ssh = ((((lane & 7) * 16) ^ (sr8 << 4)) >> 1);      // swz src (shorts)
  const unsigned short* kp0 = base + (size_t)(wave * 8 + sr8) * QKVN + DIMD + ssh;
  const unsigned short* kp1 = kp0 + (size_t)32 * QKVN;
  const unsigned short* vp0 = vbase + (size_t)(wave * 8 + sr8) * NCTX + ssh;
  const unsigned short* vp1 = vp0 + (size_t)32 * NCTX;
  const unsigned short* cp  = cbase + (tid & 31) * 2;

#define STAGE(buf)                                    \
  gll16(kp0, &(buf)[wave * 512]);                     \
  gll16(kp1, &(buf)[2048 + wave * 512]);              \
  gll16(vp0, &(buf)[4096 + wave * 512]);              \
  gll16(vp1, &(buf)[6144 + wave * 512]);              \
  if (tid < 32) gll4(cp, &(buf)[8192]);               \
  kp0 += (size_t)64 * QKVN; kp1 += (size_t)64 * QKVN; \
  vp0 += 64; vp1 += 64; cp += 64;

  // ---- Q B-frags straight from global (one-time) ----
  bf16x8 qf[2][2];
#pragma unroll
  for (int u = 0; u < 2; ++u)
#pragma unroll
    for (int h = 0; h < 2; ++h)
      qf[u][h] = *reinterpret_cast<const bf16x8*>(
          base + (size_t)(qrow0 + wq * 32 + u * 16 + l16) * QKVN + h * 32 + quad * 8);

  // ---- read-side offsets (swizzled; row&7 == l16&7 for all frag reads) ----
  const int xs = (l16 & 7) << 3;
  const int kofs0 = (wk * 32 + l16) * 64 + ((quad * 8) ^ xs);        // t adds 1024
  const int kofs1 = (wk * 32 + l16) * 64 + ((32 + quad * 8) ^ xs);
  const int vofs  = 4096 + l16 * 64 + ((wk * 32 + quad * 8) ^ xs);   // s adds 1024
  const int cofs  = 8192 + wk * 32 + quad * 8;

  // ---- prologue: stage tile 0 ----
  STAGE(lds[0]);
  __syncthreads();

  f32x4 O[2][4], accl[2];
#pragma unroll
  for (int u = 0; u < 2; ++u) {
    accl[u] = (f32x4){0.f, 0.f, 0.f, 0.f};
#pragma unroll
    for (int s = 0; s < 4; ++s) O[u][s] = (f32x4){0.f, 0.f, 0.f, 0.f};
  }

  for (int kt = 0; kt < 32; ++kt) {
    const unsigned short* bc = lds[kt & 1];
    if (kt < 31) { STAGE(lds[(kt & 1) ^ 1]); }   // DMA into other buffer
    // ---- S^T = K Q^T on wave's 32 keys x 32 queries ----
    f32x4 sfr[2][2];   // [t key-sub][u query-sub]
#pragma unroll
    for (int t = 0; t < 2; ++t) {
      const bf16x8 kf0 = *reinterpret_cast<const bf16x8*>(&bc[kofs0 + t * 1024]);
      const bf16x8 kf1 = *reinterpret_cast<const bf16x8*>(&bc[kofs1 + t * 1024]);
#pragma unroll
      for (int u = 0; u < 2; ++u) {
        f32x4 acc = (f32x4){0.f, 0.f, 0.f, 0.f};
        acc = __builtin_amdgcn_mfma_f32_16x16x32_bf16(kf0, qf[u][0], acc, 0, 0, 0);
        acc = __builtin_amdgcn_mfma_f32_16x16x32_bf16(kf1, qf[u][1], acc, 0, 0, 0);
        sfr[t][u] = acc;
      }
    }
    // ---- P = exp2(S), redistributed fully in-register ----
    bf16x8 pf[2];
#pragma unroll
    for (int u = 0; u < 2; ++u) {
      unsigned x0, x1, y0, y1;
      {
        const float e0 = exp2f(sfr[0][u][0]), e1 = exp2f(sfr[0][u][1]);
        const float e2 = exp2f(sfr[0][u][2]), e3 = exp2f(sfr[0][u][3]);
        const float f0 = exp2f(sfr[1][u][0]), f1 = exp2f(sfr[1][u][1]);
        const float f2 = exp2f(sfr[1][u][2]), f3 = exp2f(sfr[1][u][3]);
        asm("v_cvt_pk_bf16_f32 %0, %1, %2" : "=v"(x0) : "v"(e0), "v"(e1));
        asm("v_cvt_pk_bf16_f32 %0, %1, %2" : "=v"(x1) : "v"(e2), "v"(e3));
        asm("v_cvt_pk_bf16_f32 %0, %1, %2" : "=v"(y0) : "v"(f0), "v"(f1));
        asm("v_cvt_pk_bf16_f32 %0, %1, %2" : "=v"(y1) : "v"(f2), "v"(f3));
      }
      asm("v_permlane32_swap_b32 %0, %1" : "+v"(x0), "+v"(y0));
      asm("v_permlane32_swap_b32 %0, %1" : "+v"(x1), "+v"(y1));
      asm("v_permlane16_swap_b32 %0, %1" : "+v"(x0), "+v"(y0));
      asm("v_permlane16_swap_b32 %0, %1" : "+v"(x1), "+v"(y1));
      union { unsigned q[4]; bf16x8 v; } pu;
      pu.q[0] = x0; pu.q[1] = x1; pu.q[2] = y0; pu.q[3] = y1;
      pf[u] = pu.v;
    }
    // ---- O += P V' over wave's keys; denominator via c-row ----
    {
      const bf16x8 cf = *reinterpret_cast<const bf16x8*>(&bc[cofs]);
      accl[0] = __builtin_amdgcn_mfma_f32_16x16x32_bf16(pf[0], cf, accl[0], 0, 0, 0);
      accl[1] = __builtin_amdgcn_mfma_f32_16x16x32_bf16(pf[1], cf, accl[1], 0, 0, 0);
#pragma unroll
      for (int s = 0; s < 4; ++s) {
        const bf16x8 bv = *reinterpret_cast<const bf16x8*>(&bc[vofs + s * 1024]);
        O[0][s] = __builtin_amdgcn_mfma_f32_16x16x32_bf16(pf[0], bv, O[0][s], 0, 0, 0);
        O[1][s] = __builtin_amdgcn_mfma_f32_16x16x32_bf16(pf[1], bv, O[1][s], 0, 0, 0);
      }
    }
    __syncthreads();   // drains gll vmcnt -> next buffer valid; closes reads of bc
  }
#undef STAGE
  // ---- combine key-halves via Ob (bf16, stride 68) + lb (fp32), alias lds ----
  unsigned short* Ob = (unsigned short*)lds;
  float* lb = (float*)((unsigned short*)lds + 4352);
  if (wk == 1) {
#pragma unroll
    for (int u = 0; u < 2; ++u) {
#pragma unroll
      for (int s = 0; s < 4; ++s)
#pragma unroll
        for (int r = 0; r < 4; ++r)
          Ob[(wq * 32 + u * 16 + quad * 4 + r) * 68 + s * 16 + l16] = f2bits(O[u][s][r]);
      if (l16 == 0)
#pragma unroll
        for (int r = 0; r < 4; ++r)
          lb[64 + wq * 32 + u * 16 + quad * 4 + r] = accl[u][r];
    }
  } else {
#pragma unroll
    for (int u = 0; u < 2; ++u)
      if (l16 == 0)
#pragma unroll
        for (int r = 0; r < 4; ++r)
          lb[wq * 32 + u * 16 + quad * 4 + r] = accl[u][r];
  }
  __syncthreads();
  if (wk == 0) {
#pragma unroll
    for (int u = 0; u < 2; ++u)
#pragma unroll
      for (int r = 0; r < 4; ++r) {
        const int ql = wq * 32 + u * 16 + quad * 4 + r;
        const float linv = 1.f / (lb[ql] + lb[64 + ql]);
        const size_t orow = ((size_t)bi * NCTX + qrow0 + ql) * DIMD + hi * DH;
#pragma unroll
        for (int s = 0; s < 4; ++s)
          out[orow + s * 16 + l16] =
              f2bits((O[u][s][r] + bits2f(Ob[ql * 68 + s * 16 + l16])) * linv);
      }
  }
}

extern "C" void kernel_launch(void* const* d_in, const int* in_sizes, int n_in,
                              void* d_out, int out_size, void* d_ws, size_t ws_size,
                              hipStream_t stream) {
  const float* x     = (const float*)d_in[0];
  const float* pose  = (const float*)d_in[1];
  const float* gam   = (const float*)d_in[2];
  const float* bet   = (const float*)d_in[3];
  const float* wqkv  = (const float*)d_in[4];
  const float* wout  = (const float*)d_in[5];
  const float* betap = (const float*)d_in[6];
  float* out = (float*)d_out;

  unsigned short* xn    = (unsigned short*)d_ws;             // 8 MB (reused as aout)
  unsigned short* qkvb  = xn + (size_t)NROWS * DIMD;         // 24 MB
  unsigned short* wqkvT = qkvb + (size_t)NROWS * QKVN;       // 1.5 MB
  unsigned short* woutT = wqkvT + (size_t)QKVN * DIMD;       // 0.5 MB
  unsigned short* vtg   = woutT + (size_t)DIMD * DIMD;       // 8 MB  c-scaled V^T
  unsigned short* cexp  = vtg + (size_t)NB * NH * DH * NCTX; // 16 KB
  unsigned short* aout  = xn;                                // alias: xn dead after GEMM1

  ln_kernel<<<NROWS / 4, 256, 0, stream>>>(x, gam, bet, xn);
  tconv_kernel<<<dim3(QKVN / 64, DIMD / 64, 2), 256, 0, stream>>>(
      wqkv, wqkvT, wout, woutT);
  ggemm_kernel<unsigned short, true><<<dim3(QKVN / 128, NROWS / 128), 256, 0, stream>>>(
      xn, wqkvT, qkvb, NROWS, QKVN, DIMD);
  vtrans_kernel<<<dim3(NCTX / 64, NH, NB), 256, 0, stream>>>(
      qkvb, pose, betap, cexp, vtg);
  fattn_kernel<<<dim3(NCTX / 64, NH, NB), 256, 0, stream>>>(qkvb, vtg, cexp, aout);
  mgemm_kernel<float, false><<<dim3(DIMD / 128, NROWS / 128), 256, 0, stream>>>(
      aout, woutT, out, NROWS, DIMD, DIMD);
}